// Round 13
// baseline (254.356 us; speedup 1.0000x reference)
//
#include <hip/hip_runtime.h>
#include <hip/hip_bf16.h>

#define FEAT 128
#define RBITS 12
#define RSIZE 4096           // partition width (16 KB LDS of u32)
#define NCHUNK 32            // edge chunks

typedef __attribute__((ext_vector_type(8))) short short8;
typedef __attribute__((ext_vector_type(4))) short short4v;
typedef __attribute__((ext_vector_type(4))) float f32x4;
typedef __attribute__((ext_vector_type(2))) unsigned uint2v;

__device__ __forceinline__ ushort f2bf(float f) {
    union { float f; unsigned u; } v; v.f = f;
    unsigned u = v.u;
    unsigned r = 0x7fffu + ((u >> 16) & 1u);
    return (ushort)((u + r) >> 16);
}
__device__ __forceinline__ float bf2f(short s) {
    union { unsigned u; float f; } v;
    v.u = ((unsigned)(ushort)s) << 16;
    return v.f;
}

// ---- fp8 e4m3 (OCP) with x64 pre-scale folded in ----
// enc: store round(f*64) as e4m3 (RNE, saturate to 448, flush sub-2^-6 to 0)
__device__ __forceinline__ unsigned char enc8(float f) {
    union { float f; unsigned u; } v; v.f = f * 64.0f;
    unsigned b = v.u;
    unsigned s = (b >> 24) & 0x80u;
    b &= 0x7fffffffu;
    b += 0x7FFFFu + ((b >> 20) & 1u);      // RNE at bit 20 (3-bit mantissa)
    int e4 = (int)((b >> 23) & 0xFFu) - 120;
    if (e4 <= 0)  return (unsigned char)s;            // tiny -> 0
    if (e4 >= 16) return (unsigned char)(s | 0x7Eu);  // saturate 448 (not NaN)
    return (unsigned char)(s | ((unsigned)e4 << 3) | ((b >> 20) & 7u));
}
// dec: e4m3 byte -> f32, with 1/64 folded into the exponent constant (2^120/2^6 = 2^114)
__device__ __forceinline__ float dec8(unsigned byte) {
    union { unsigned u; float f; } v;
    v.u = ((byte & 0x80u) << 24) | ((byte & 0x7Fu) << 20);
    return v.f * 0x1p114f;
}

// ---------------------------------------------------------------- A: partial histograms (LDS atomics only)
__global__ __launch_bounds__(256)
void hist_kernel(const int* __restrict__ src, const int* __restrict__ dst,
                 unsigned* __restrict__ partial, int E, int CS)
{
    __shared__ unsigned hist[RSIZE];
    const int c = blockIdx.x, p = blockIdx.y, job = blockIdx.z;
    const int* __restrict__ idx = job ? dst : src;
    for (int r = threadIdx.x; r < RSIZE; r += 256) hist[r] = 0;
    __syncthreads();
    const int e0 = c * CS, e1 = min(E, e0 + CS);
    const int eA = e0 + ((e1 - e0) & ~3);
    for (int e = e0 + threadIdx.x * 4; e + 4 <= e1; e += 1024) {
        int4 v = *(const int4*)(idx + e);
        if ((v.x >> RBITS) == p) atomicAdd(&hist[v.x & (RSIZE - 1)], 1u);
        if ((v.y >> RBITS) == p) atomicAdd(&hist[v.y & (RSIZE - 1)], 1u);
        if ((v.z >> RBITS) == p) atomicAdd(&hist[v.z & (RSIZE - 1)], 1u);
        if ((v.w >> RBITS) == p) atomicAdd(&hist[v.w & (RSIZE - 1)], 1u);
    }
    for (int e = eA + threadIdx.x; e < e1; e += 256) {
        int v = idx[e];
        if ((v >> RBITS) == p) atomicAdd(&hist[v & (RSIZE - 1)], 1u);
    }
    __syncthreads();
    unsigned* outp = partial +
        (((size_t)job * gridDim.y + p) * NCHUNK + c) * RSIZE;
    for (int r = threadIdx.x; r < RSIZE; r += 256) outp[r] = hist[r];
}

// ---------------------------------------------------------------- B: merge (+ fused block sums)
__global__ __launch_bounds__(256)
void merge_kernel(const unsigned* __restrict__ partialOut, unsigned* __restrict__ partialIn,
                  int* __restrict__ cntIn, float* __restrict__ normOut,
                  float* __restrict__ normIn, int* __restrict__ blockSums, int N)
{
    __shared__ int sh[256];
    const int n = blockIdx.x * 256 + threadIdx.x;
    unsigned off = 0;
    if (n < N) {
        const int p = n >> RBITS, r = n & (RSIZE - 1);
        const size_t base = (size_t)p * NCHUNK * RSIZE + r;
        unsigned so = 0;
#pragma unroll 8
        for (int c = 0; c < NCHUNK; ++c) so += partialOut[base + (size_t)c * RSIZE];
#pragma unroll 8
        for (int c = 0; c < NCHUNK; ++c) {
            size_t i = base + (size_t)c * RSIZE;
            unsigned t = partialIn[i];
            partialIn[i] = off;
            off += t;
        }
        cntIn[n]   = (int)off;
        normIn[n]  = off ? rsqrtf((float)off) : 0.0f;
        normOut[n] = so  ? rsqrtf((float)so)  : 0.0f;
    }
    sh[threadIdx.x] = (int)off;
    __syncthreads();
    for (int o = 128; o > 0; o >>= 1) {
        if (threadIdx.x < o) sh[threadIdx.x] += sh[threadIdx.x + o];
        __syncthreads();
    }
    if (threadIdx.x == 0) blockSums[blockIdx.x] = sh[0];
}

// ---------------------------------------------------------------- rowStart
__global__ __launch_bounds__(256)
void rowstart_kernel(const int* __restrict__ cntIn, const int* __restrict__ blockSums,
                     int* __restrict__ rowStart, int N, int NB, int E)
{
    __shared__ int bs[256];
    __shared__ int bse[256];
    __shared__ int sh[256];
    const int t = threadIdx.x;
    int bv = (t < NB) ? blockSums[t] : 0;
    bs[t] = bv;
    __syncthreads();
    for (int off = 1; off < 256; off <<= 1) {
        int u = (t >= off) ? bs[t - off] : 0;
        __syncthreads();
        bs[t] += u;
        __syncthreads();
    }
    bse[t] = bs[t] - bv;
    __syncthreads();

    const int i = blockIdx.x * 256 + t;
    int v = (i < N) ? cntIn[i] : 0;
    sh[t] = v;
    __syncthreads();
    for (int off = 1; off < 256; off <<= 1) {
        int u = (t >= off) ? sh[t - off] : 0;
        __syncthreads();
        sh[t] += u;
        __syncthreads();
    }
    if (i < N) rowStart[i] = bse[blockIdx.x] + sh[t] - v;
    if (blockIdx.x == 0 && t == 0) rowStart[N] = E;
}

// ---------------------------------------------------------------- fill: LDS cursor counting sort
__global__ __launch_bounds__(256)
void fill_kernel(const int* __restrict__ src, const int* __restrict__ dst,
                 const int* __restrict__ rowStart, const unsigned* __restrict__ chunkOff,
                 int* __restrict__ csrSrc, int N, int E, int CS)
{
    __shared__ unsigned cursor[RSIZE];
    const int c = blockIdx.x, p = blockIdx.y;
    const unsigned* co = chunkOff + ((size_t)p * NCHUNK + c) * RSIZE;
    for (int r = threadIdx.x; r < RSIZE; r += 256) {
        int n = (p << RBITS) + r;
        cursor[r] = (n < N) ? (unsigned)rowStart[n] + co[r] : 0u;
    }
    __syncthreads();
    const int e0 = c * CS, e1 = min(E, e0 + CS);
    const int eA = e0 + ((e1 - e0) & ~3);
    for (int e = e0 + threadIdx.x * 4; e + 4 <= e1; e += 1024) {
        int4 d = *(const int4*)(dst + e);
        if ((d.x >> RBITS) == p) { unsigned q = atomicAdd(&cursor[d.x & (RSIZE - 1)], 1u); csrSrc[q] = src[e]; }
        if ((d.y >> RBITS) == p) { unsigned q = atomicAdd(&cursor[d.y & (RSIZE - 1)], 1u); csrSrc[q] = src[e + 1]; }
        if ((d.z >> RBITS) == p) { unsigned q = atomicAdd(&cursor[d.z & (RSIZE - 1)], 1u); csrSrc[q] = src[e + 2]; }
        if ((d.w >> RBITS) == p) { unsigned q = atomicAdd(&cursor[d.w & (RSIZE - 1)], 1u); csrSrc[q] = src[e + 3]; }
    }
    for (int e = eA + threadIdx.x; e < e1; e += 256) {
        int d = dst[e];
        if ((d >> RBITS) == p) { unsigned q = atomicAdd(&cursor[d & (RSIZE - 1)], 1u); csrSrc[q] = src[e]; }
    }
}

// ---------------------------------------------------------------- MFMA GEMM (bf16), fp32 input (layer 1); fp8 output
__global__ __launch_bounds__(512)
void gemm_mfma_kernel(const float* __restrict__ Ain, const float* __restrict__ W,
                      const float* __restrict__ scale, unsigned char* __restrict__ C,
                      int M, int nStrips)
{
    __shared__ ushort WTAs[64 * 132]; // half W^T staging, then As[64][132]
    __shared__ float  sScale[64];
    ushort* WT = WTAs;
    ushort* As = WTAs;

    const int tid  = threadIdx.x;
    const int wv   = tid >> 6;
    const int lane = tid & 63;
    const int rowHalf = wv >> 2;
    const int colQ = wv & 3;
    const int l15  = lane & 15;
    const int quad = lane >> 4;

    short8 bfrag[2][4];
#pragma unroll
    for (int hh = 0; hh < 2; ++hh) {
        if (hh) __syncthreads();
        for (int it = 0; it < 4; ++it) {
            int fid = tid + (it << 9);
            int k   = fid >> 4;
            int cl  = (fid & 15) << 2;
            float4 w = *(const float4*)(W + (size_t)k * FEAT + hh * 64 + cl);
            WT[(cl + 0) * 132 + k] = f2bf(w.x);
            WT[(cl + 1) * 132 + k] = f2bf(w.y);
            WT[(cl + 2) * 132 + k] = f2bf(w.z);
            WT[(cl + 3) * 132 + k] = f2bf(w.w);
        }
        __syncthreads();
        if (((wv >> 1) & 1) == hh) {
            int cq = wv & 1;
#pragma unroll
            for (int ct = 0; ct < 2; ++ct) {
                int col = cq * 32 + ct * 16 + l15;
#pragma unroll
                for (int kst = 0; kst < 4; ++kst) {
                    int k = kst * 32 + quad * 8;
                    short4v lo = *(const short4v*)&WT[col * 132 + k];
                    short4v hi = *(const short4v*)&WT[col * 132 + k + 4];
                    bfrag[ct][kst] = __builtin_shufflevector(lo, hi, 0, 1, 2, 3, 4, 5, 6, 7);
                }
            }
        }
    }

    for (int s = blockIdx.x; s < nStrips; s += gridDim.x) {
        const int row0 = s << 6;
        __syncthreads();

#pragma unroll
        for (int it = 0; it < 2; ++it) {
            int fid = tid + (it << 9);
            int r   = fid >> 4;
            int seg = (fid & 15) << 3;
            int grow = row0 + r;
            short4v lo = {0, 0, 0, 0}, hi = {0, 0, 0, 0};
            if (grow < M) {
                const float* pa = Ain + (size_t)grow * FEAT + seg;
                float4 u0 = *(const float4*)(pa);
                float4 u1 = *(const float4*)(pa + 4);
                lo[0] = (short)f2bf(u0.x); lo[1] = (short)f2bf(u0.y);
                lo[2] = (short)f2bf(u0.z); lo[3] = (short)f2bf(u0.w);
                hi[0] = (short)f2bf(u1.x); hi[1] = (short)f2bf(u1.y);
                hi[2] = (short)f2bf(u1.z); hi[3] = (short)f2bf(u1.w);
            }
            *(short4v*)&As[r * 132 + seg]     = lo;
            *(short4v*)&As[r * 132 + seg + 4] = hi;
        }
        if (tid < 64) {
            int grow = row0 + tid;
            sScale[tid] = (grow < M) ? scale[grow] : 0.0f;
        }
        __syncthreads();

        f32x4 acc[2][2] = {};
#pragma unroll
        for (int kst = 0; kst < 4; ++kst) {
            int k = kst * 32 + quad * 8;
            short8 af[2];
#pragma unroll
            for (int rt = 0; rt < 2; ++rt) {
                int row = rowHalf * 32 + rt * 16 + l15;
                short4v lo = *(const short4v*)&As[row * 132 + k];
                short4v hi = *(const short4v*)&As[row * 132 + k + 4];
                af[rt] = __builtin_shufflevector(lo, hi, 0, 1, 2, 3, 4, 5, 6, 7);
            }
#pragma unroll
            for (int rt = 0; rt < 2; ++rt)
#pragma unroll
                for (int ct = 0; ct < 2; ++ct)
                    acc[rt][ct] = __builtin_amdgcn_mfma_f32_16x16x32_bf16(
                        af[rt], bfrag[ct][kst], acc[rt][ct], 0, 0, 0);
        }

#pragma unroll
        for (int rt = 0; rt < 2; ++rt) {
            int rbase = rowHalf * 32 + rt * 16 + quad * 4;
#pragma unroll
            for (int reg = 0; reg < 4; ++reg) {
                int rl = rbase + reg;
                int grow = row0 + rl;
                if (grow < M) {
                    float sc = sScale[rl];
#pragma unroll
                    for (int ct = 0; ct < 2; ++ct) {
                        int col = colQ * 32 + ct * 16 + l15;
                        C[(size_t)grow * FEAT + col] = enc8(acc[rt][ct][reg] * sc);
                    }
                }
            }
        }
    }
}

// ---------------------------------------------------------------- gather inner over fp8 rows
// 16 lanes x 8B per row (8 fp8 feats per lane); 8 rows in flight; decode has 1/64 folded in.
__device__ __forceinline__ void gather_row(const unsigned char* __restrict__ t,
                                           const int* __restrict__ csrSrc,
                                           int s, int e, int gl, int h, int li,
                                           float a[8])
{
    for (int base = s; base < e; base += 32) {
        const int m = min(32, e - base);
        int idx = (base + gl < e) ? csrSrc[base + gl] : 0;
        for (int j0 = 0; j0 < m; j0 += 16) {
            int sx[8];
#pragma unroll
            for (int q = 0; q < 8; ++q)
                sx[q] = __shfl(idx, j0 + h + 2 * q, 32);
            uint2v w[8];
#pragma unroll
            for (int q = 0; q < 8; ++q) {
                w[q] = (uint2v){0u, 0u};
                if (j0 + h + 2 * q < m)
                    w[q] = *(const uint2v*)(t + (size_t)sx[q] * FEAT + li * 8);
            }
#pragma unroll
            for (int k = 0; k < 4; ++k) {
                const int sh = 8 * k;
                a[k]     += ((dec8((w[0][0] >> sh) & 0xFFu) + dec8((w[1][0] >> sh) & 0xFFu))
                           + (dec8((w[2][0] >> sh) & 0xFFu) + dec8((w[3][0] >> sh) & 0xFFu)))
                          + ((dec8((w[4][0] >> sh) & 0xFFu) + dec8((w[5][0] >> sh) & 0xFFu))
                           + (dec8((w[6][0] >> sh) & 0xFFu) + dec8((w[7][0] >> sh) & 0xFFu)));
                a[k + 4] += ((dec8((w[0][1] >> sh) & 0xFFu) + dec8((w[1][1] >> sh) & 0xFFu))
                           + (dec8((w[2][1] >> sh) & 0xFFu) + dec8((w[3][1] >> sh) & 0xFFu)))
                          + ((dec8((w[4][1] >> sh) & 0xFFu) + dec8((w[5][1] >> sh) & 0xFFu))
                           + (dec8((w[6][1] >> sh) & 0xFFu) + dec8((w[7][1] >> sh) & 0xFFu)));
            }
        }
    }
}

// ---------------------------------------------------------------- fusedA: gather(t1 fp8)+relu -> GEMM(W2)*normOut -> t2 fp8
__global__ __launch_bounds__(512)
void fusedA_kernel(const unsigned char* __restrict__ t1, const int* __restrict__ rowStart,
                   const int* __restrict__ csrSrc, const float* __restrict__ normIn,
                   const float* __restrict__ bias, const float* __restrict__ W,
                   const float* __restrict__ normOut, unsigned char* __restrict__ t2, int N)
{
    __shared__ ushort WTAs[64 * 132]; // half W2^T staging, then As[64][132]
    __shared__ float  sScale[64];
    ushort* WT = WTAs;
    ushort* As = WTAs;

    const int tid  = threadIdx.x;
    const int wv   = tid >> 6;
    const int lane = tid & 63;
    const int rowHalf = wv >> 2;
    const int colQ = wv & 3;
    const int l15  = lane & 15;
    const int quad = lane >> 4;
    const int row0 = blockIdx.x << 6;

    short8 bfrag[2][4];
#pragma unroll
    for (int hh = 0; hh < 2; ++hh) {
        if (hh) __syncthreads();
        for (int it = 0; it < 4; ++it) {
            int fid = tid + (it << 9);
            int k   = fid >> 4;
            int cl  = (fid & 15) << 2;
            float4 w = *(const float4*)(W + (size_t)k * FEAT + hh * 64 + cl);
            WT[(cl + 0) * 132 + k] = f2bf(w.x);
            WT[(cl + 1) * 132 + k] = f2bf(w.y);
            WT[(cl + 2) * 132 + k] = f2bf(w.z);
            WT[(cl + 3) * 132 + k] = f2bf(w.w);
        }
        __syncthreads();
        if (((wv >> 1) & 1) == hh) {
            int cq = wv & 1;
#pragma unroll
            for (int ct = 0; ct < 2; ++ct) {
                int col = cq * 32 + ct * 16 + l15;
#pragma unroll
                for (int kst = 0; kst < 4; ++kst) {
                    int k = kst * 32 + quad * 8;
                    short4v lo = *(const short4v*)&WT[col * 132 + k];
                    short4v hi = *(const short4v*)&WT[col * 132 + k + 4];
                    bfrag[ct][kst] = __builtin_shufflevector(lo, hi, 0, 1, 2, 3, 4, 5, 6, 7);
                }
            }
        }
    }
    if (tid < 64) {
        int grow = row0 + tid;
        sScale[tid] = (grow < N) ? normOut[grow] : 0.0f;
    }
    __syncthreads();  // all WT reads done before As (alias) is written

    // gather phase: 16 groups of 32 lanes; group g handles rows g, g+16, g+32, g+48
    {
        const int g    = tid >> 5;
        const int gl   = tid & 31;
        const int h    = gl >> 4;
        const int li   = gl & 15;
        const float4 b0 = *(const float4*)(bias + li * 8);
        const float4 b1 = *(const float4*)(bias + li * 8 + 4);
        for (int i = g; i < 64; i += 16) {
            const int node = row0 + i;
            float a[8] = {0.f, 0.f, 0.f, 0.f, 0.f, 0.f, 0.f, 0.f};
            if (node < N) {
                gather_row(t1, csrSrc, rowStart[node], rowStart[node + 1], gl, h, li, a);
            }
#pragma unroll
            for (int k = 0; k < 8; ++k)
                a[k] += __shfl_xor(a[k], 16, 32);
            if (h == 0) {
                short8 o = {0, 0, 0, 0, 0, 0, 0, 0};
                if (node < N) {
                    float ni = normIn[node];
                    o[0] = (short)f2bf(fmaxf(fmaf(a[0], ni, b0.x), 0.0f));
                    o[1] = (short)f2bf(fmaxf(fmaf(a[1], ni, b0.y), 0.0f));
                    o[2] = (short)f2bf(fmaxf(fmaf(a[2], ni, b0.z), 0.0f));
                    o[3] = (short)f2bf(fmaxf(fmaf(a[3], ni, b0.w), 0.0f));
                    o[4] = (short)f2bf(fmaxf(fmaf(a[4], ni, b1.x), 0.0f));
                    o[5] = (short)f2bf(fmaxf(fmaf(a[5], ni, b1.y), 0.0f));
                    o[6] = (short)f2bf(fmaxf(fmaf(a[6], ni, b1.z), 0.0f));
                    o[7] = (short)f2bf(fmaxf(fmaf(a[7], ni, b1.w), 0.0f));
                }
                *(short8*)&As[i * 132 + li * 8] = o;
            }
        }
    }
    __syncthreads();

    // MFMA phase
    f32x4 acc[2][2] = {};
#pragma unroll
    for (int kst = 0; kst < 4; ++kst) {
        int k = kst * 32 + quad * 8;
        short8 af[2];
#pragma unroll
        for (int rt = 0; rt < 2; ++rt) {
            int row = rowHalf * 32 + rt * 16 + l15;
            short4v lo = *(const short4v*)&As[row * 132 + k];
            short4v hi = *(const short4v*)&As[row * 132 + k + 4];
            af[rt] = __builtin_shufflevector(lo, hi, 0, 1, 2, 3, 4, 5, 6, 7);
        }
#pragma unroll
        for (int rt = 0; rt < 2; ++rt)
#pragma unroll
            for (int ct = 0; ct < 2; ++ct)
                acc[rt][ct] = __builtin_amdgcn_mfma_f32_16x16x32_bf16(
                    af[rt], bfrag[ct][kst], acc[rt][ct], 0, 0, 0);
    }

#pragma unroll
    for (int rt = 0; rt < 2; ++rt) {
        int rbase = rowHalf * 32 + rt * 16 + quad * 4;
#pragma unroll
        for (int reg = 0; reg < 4; ++reg) {
            int rl = rbase + reg;
            int grow = row0 + rl;
            if (grow < N) {
                float sc = sScale[rl];
#pragma unroll
                for (int ct = 0; ct < 2; ++ct) {
                    int col = colQ * 32 + ct * 16 + l15;
                    t2[(size_t)grow * FEAT + col] = enc8(acc[rt][ct][reg] * sc);
                }
            }
        }
    }
}

// ---------------------------------------------------------------- fusedB: gather(t2 fp8)+relu -> per-block column partials
__global__ __launch_bounds__(256)
void fusedB_kernel(const unsigned char* __restrict__ t2, const int* __restrict__ rowStart,
                   const int* __restrict__ csrSrc, const float* __restrict__ normIn,
                   const float* __restrict__ bias, float* __restrict__ partials, int N)
{
    const int g    = threadIdx.x >> 5;
    const int gl   = threadIdx.x & 31;
    const int h    = gl >> 4;
    const int li   = gl & 15;
    const float4 b0 = *(const float4*)(bias + li * 8);
    const float4 b1 = *(const float4*)(bias + li * 8 + 4);
    const int stride = gridDim.x * 8;

    float racc[8] = {0.f, 0.f, 0.f, 0.f, 0.f, 0.f, 0.f, 0.f};
    for (int node = blockIdx.x * 8 + g; node < N; node += stride) {
        float a[8] = {0.f, 0.f, 0.f, 0.f, 0.f, 0.f, 0.f, 0.f};
        gather_row(t2, csrSrc, rowStart[node], rowStart[node + 1], gl, h, li, a);
#pragma unroll
        for (int k = 0; k < 8; ++k)
            a[k] += __shfl_xor(a[k], 16, 32);
        if (h == 0) {
            float ni = normIn[node];
            racc[0] += fmaxf(fmaf(a[0], ni, b0.x), 0.0f);
            racc[1] += fmaxf(fmaf(a[1], ni, b0.y), 0.0f);
            racc[2] += fmaxf(fmaf(a[2], ni, b0.z), 0.0f);
            racc[3] += fmaxf(fmaf(a[3], ni, b0.w), 0.0f);
            racc[4] += fmaxf(fmaf(a[4], ni, b1.x), 0.0f);
            racc[5] += fmaxf(fmaf(a[5], ni, b1.y), 0.0f);
            racc[6] += fmaxf(fmaf(a[6], ni, b1.z), 0.0f);
            racc[7] += fmaxf(fmaf(a[7], ni, b1.w), 0.0f);
        }
    }

    __shared__ float colsh[8][128];
    if (h == 0) {
#pragma unroll
        for (int k = 0; k < 8; ++k) colsh[g][li * 8 + k] = racc[k];
    }
    __syncthreads();
    if (threadIdx.x < 128) {
        float sum = 0.f;
#pragma unroll
        for (int gg = 0; gg < 8; ++gg) sum += colsh[gg][threadIdx.x];
        partials[(size_t)blockIdx.x * 128 + threadIdx.x] = sum;
    }
}

// ---------------------------------------------------------------- final: parallel reduce of partials + readout
__global__ __launch_bounds__(1024)
void final_kernel(const float* __restrict__ partials, const float* __restrict__ Wr,
                  const float* __restrict__ br, float* __restrict__ out, float invN, int G)
{
    __shared__ float cs[128];
    __shared__ float s0[128], s1[128];
    if (threadIdx.x < 128) cs[threadIdx.x] = 0.0f;
    __syncthreads();

    const int c4 = (threadIdx.x & 31) << 2;
    const int rg = threadIdx.x >> 5;
    f32x4 acc = {0.f, 0.f, 0.f, 0.f};
    for (int b = rg; b < G; b += 32) {
        f32x4 v = *(const f32x4*)(partials + (size_t)b * 128 + c4);
        acc += v;
    }
    atomicAdd(&cs[c4 + 0], acc[0]);
    atomicAdd(&cs[c4 + 1], acc[1]);
    atomicAdd(&cs[c4 + 2], acc[2]);
    atomicAdd(&cs[c4 + 3], acc[3]);
    __syncthreads();

    const int j = threadIdx.x;
    if (j < 128) {
        float hg = cs[j] * invN;
        s0[j] = hg * Wr[2 * j + 0];
        s1[j] = hg * Wr[2 * j + 1];
    }
    __syncthreads();
    for (int off = 64; off > 0; off >>= 1) {
        if (j < off) { s0[j] += s0[j + off]; s1[j] += s1[j + off]; }
        __syncthreads();
    }
    if (j == 0) {
        out[0] = s0[0] + br[0];
        out[1] = s1[0] + br[1];
    }
}

// ---------------------------------------------------------------- launch
extern "C" void kernel_launch(void* const* d_in, const int* in_sizes, int n_in,
                              void* d_out, int out_size, void* d_ws, size_t ws_size,
                              hipStream_t stream)
{
    const float* x   = (const float*)d_in[0];
    const int*   src = (const int*)d_in[1];
    const int*   dst = (const int*)d_in[2];
    const float* W1  = (const float*)d_in[3];
    const float* b1  = (const float*)d_in[4];
    const float* W2  = (const float*)d_in[5];
    const float* b2  = (const float*)d_in[6];
    const float* Wr  = (const float*)d_in[7];
    const float* br  = (const float*)d_in[8];
    float* out = (float*)d_out;

    const int N = in_sizes[0] / FEAT;         // 50000
    const int E = in_sizes[1];                // 640000
    const int NP = ((N + 255) / 256) * 256;
    const int NB = (N + 255) / 256;           // 196
    const int P  = (N + RSIZE - 1) / RSIZE;   // 13
    const int CS = (((E + NCHUNK - 1) / NCHUNK) + 3) & ~3;  // 4-aligned chunk
    const int GB = 1024;                      // fusedB blocks

    // workspace layout
    char* p = (char*)d_ws;
    unsigned* partial = (unsigned*)p;    p += (size_t)2 * P * NCHUNK * RSIZE * 4;
    int*    blockSums = (int*)p;         p += 256 * 4;
    int*    cntIn     = (int*)p;         p += (size_t)NP * 4;
    float*  normOut   = (float*)p;       p += (size_t)NP * 4;
    float*  normIn    = (float*)p;       p += (size_t)NP * 4;
    int*    rowStart  = (int*)p;         p += (size_t)(NP + 64) * 4;
    int*    csrSrc    = (int*)p;         p += (size_t)E * 4;
    float*  partials  = (float*)p;       p += (size_t)GB * 128 * 4;
    unsigned char* bufT1 = (unsigned char*)p;  p += (size_t)N * FEAT;
    unsigned char* bufT2 = (unsigned char*)p;  p += (size_t)N * FEAT;

    unsigned* partialOut = partial;                                  // job 0 (src)
    unsigned* partialIn  = partial + (size_t)P * NCHUNK * RSIZE;     // job 1 (dst)

    // CSR + degree pipeline (LDS-partitioned, no memory-side atomics)
    hist_kernel<<<dim3(NCHUNK, P, 2), 256, 0, stream>>>(src, dst, partial, E, CS);
    merge_kernel<<<NB, 256, 0, stream>>>(partialOut, partialIn, cntIn, normOut, normIn, blockSums, N);
    rowstart_kernel<<<NB, 256, 0, stream>>>(cntIn, blockSums, rowStart, N, NB, E);
    fill_kernel<<<dim3(NCHUNK, P), 256, 0, stream>>>(src, dst, rowStart, partialIn, csrSrc, N, E, CS);

    const int nStrips = (N + 63) / 64;        // 782

    // layer 1 GEMM: t1 = fp8((x W1) * normOut * 64)
    gemm_mfma_kernel<<<nStrips, 512, 0, stream>>>(x, W1, normOut, bufT1, N, nStrips);

    // layer 1 gather + relu + layer 2 GEMM fused: t2 = fp8((relu(Agg(t1)*normIn+b1) W2) * normOut * 64)
    fusedA_kernel<<<nStrips, 512, 0, stream>>>(bufT1, rowStart, csrSrc, normIn, b1, W2, normOut, bufT2, N);

    // layer 2 gather + relu + column partial sums
    fusedB_kernel<<<GB, 256, 0, stream>>>(bufT2, rowStart, csrSrc, normIn, b2, partials, N);

    // parallel reduce + readout
    final_kernel<<<1, 1024, 0, stream>>>(partials, Wr, br, out, 1.0f / (float)N, GB);
}

// Round 14
// 211.953 us; speedup vs baseline: 1.2001x; 1.2001x over previous
//
#include <hip/hip_runtime.h>
#include <hip/hip_bf16.h>

#define FEAT 128
#define RBITS 12
#define RSIZE 4096           // partition width (16 KB LDS of u32)
#define NCHUNK 32            // edge chunks

typedef __attribute__((ext_vector_type(8))) short short8;
typedef __attribute__((ext_vector_type(4))) short short4v;
typedef __attribute__((ext_vector_type(4))) float f32x4;
typedef __attribute__((ext_vector_type(2))) float f32x2;
typedef __attribute__((ext_vector_type(2))) unsigned uint2v;

__device__ __forceinline__ ushort f2bf(float f) {
    union { float f; unsigned u; } v; v.f = f;
    unsigned u = v.u;
    unsigned r = 0x7fffu + ((u >> 16) & 1u);
    return (ushort)((u + r) >> 16);
}
__device__ __forceinline__ float bf2f(short s) {
    union { unsigned u; float f; } v;
    v.u = ((unsigned)(ushort)s) << 16;
    return v.f;
}

// ---- fp8 e4m3 via HW converts (gfx940+ fp8-conversion-insts) ----
// x64 pre-scale is folded into normOut (x64) / normIn (/64) at merge time.
__device__ __forceinline__ unsigned char enc8(float f) {
    int r = __builtin_amdgcn_cvt_pk_fp8_f32(f, f, 0, false);
    return (unsigned char)(r & 0xFF);
}

// ---------------------------------------------------------------- A: partial histograms (LDS atomics only)
__global__ __launch_bounds__(256)
void hist_kernel(const int* __restrict__ src, const int* __restrict__ dst,
                 unsigned* __restrict__ partial, int E, int CS)
{
    __shared__ unsigned hist[RSIZE];
    const int c = blockIdx.x, p = blockIdx.y, job = blockIdx.z;
    const int* __restrict__ idx = job ? dst : src;
    for (int r = threadIdx.x; r < RSIZE; r += 256) hist[r] = 0;
    __syncthreads();
    const int e0 = c * CS, e1 = min(E, e0 + CS);
    const int eA = e0 + ((e1 - e0) & ~3);
    for (int e = e0 + threadIdx.x * 4; e + 4 <= e1; e += 1024) {
        int4 v = *(const int4*)(idx + e);
        if ((v.x >> RBITS) == p) atomicAdd(&hist[v.x & (RSIZE - 1)], 1u);
        if ((v.y >> RBITS) == p) atomicAdd(&hist[v.y & (RSIZE - 1)], 1u);
        if ((v.z >> RBITS) == p) atomicAdd(&hist[v.z & (RSIZE - 1)], 1u);
        if ((v.w >> RBITS) == p) atomicAdd(&hist[v.w & (RSIZE - 1)], 1u);
    }
    for (int e = eA + threadIdx.x; e < e1; e += 256) {
        int v = idx[e];
        if ((v >> RBITS) == p) atomicAdd(&hist[v & (RSIZE - 1)], 1u);
    }
    __syncthreads();
    unsigned* outp = partial +
        (((size_t)job * gridDim.y + p) * NCHUNK + c) * RSIZE;
    for (int r = threadIdx.x; r < RSIZE; r += 256) outp[r] = hist[r];
}

// ---------------------------------------------------------------- B: merge (+ fused block sums)
// normOut carries x64 (fp8 encode pre-scale), normIn carries /64 (decode post-scale).
__global__ __launch_bounds__(256)
void merge_kernel(const unsigned* __restrict__ partialOut, unsigned* __restrict__ partialIn,
                  int* __restrict__ cntIn, float* __restrict__ normOut,
                  float* __restrict__ normIn, int* __restrict__ blockSums, int N)
{
    __shared__ int sh[256];
    const int n = blockIdx.x * 256 + threadIdx.x;
    unsigned off = 0;
    if (n < N) {
        const int p = n >> RBITS, r = n & (RSIZE - 1);
        const size_t base = (size_t)p * NCHUNK * RSIZE + r;
        unsigned so = 0;
#pragma unroll 8
        for (int c = 0; c < NCHUNK; ++c) so += partialOut[base + (size_t)c * RSIZE];
#pragma unroll 8
        for (int c = 0; c < NCHUNK; ++c) {
            size_t i = base + (size_t)c * RSIZE;
            unsigned t = partialIn[i];
            partialIn[i] = off;
            off += t;
        }
        cntIn[n]   = (int)off;
        normIn[n]  = off ? rsqrtf((float)off) * (1.0f / 64.0f) : 0.0f;
        normOut[n] = so  ? rsqrtf((float)so)  * 64.0f          : 0.0f;
    }
    sh[threadIdx.x] = (int)off;
    __syncthreads();
    for (int o = 128; o > 0; o >>= 1) {
        if (threadIdx.x < o) sh[threadIdx.x] += sh[threadIdx.x + o];
        __syncthreads();
    }
    if (threadIdx.x == 0) blockSums[blockIdx.x] = sh[0];
}

// ---------------------------------------------------------------- rowStart
__global__ __launch_bounds__(256)
void rowstart_kernel(const int* __restrict__ cntIn, const int* __restrict__ blockSums,
                     int* __restrict__ rowStart, int N, int NB, int E)
{
    __shared__ int bs[256];
    __shared__ int bse[256];
    __shared__ int sh[256];
    const int t = threadIdx.x;
    int bv = (t < NB) ? blockSums[t] : 0;
    bs[t] = bv;
    __syncthreads();
    for (int off = 1; off < 256; off <<= 1) {
        int u = (t >= off) ? bs[t - off] : 0;
        __syncthreads();
        bs[t] += u;
        __syncthreads();
    }
    bse[t] = bs[t] - bv;
    __syncthreads();

    const int i = blockIdx.x * 256 + t;
    int v = (i < N) ? cntIn[i] : 0;
    sh[t] = v;
    __syncthreads();
    for (int off = 1; off < 256; off <<= 1) {
        int u = (t >= off) ? sh[t - off] : 0;
        __syncthreads();
        sh[t] += u;
        __syncthreads();
    }
    if (i < N) rowStart[i] = bse[blockIdx.x] + sh[t] - v;
    if (blockIdx.x == 0 && t == 0) rowStart[N] = E;
}

// ---------------------------------------------------------------- fill: LDS cursor counting sort
__global__ __launch_bounds__(256)
void fill_kernel(const int* __restrict__ src, const int* __restrict__ dst,
                 const int* __restrict__ rowStart, const unsigned* __restrict__ chunkOff,
                 int* __restrict__ csrSrc, int N, int E, int CS)
{
    __shared__ unsigned cursor[RSIZE];
    const int c = blockIdx.x, p = blockIdx.y;
    const unsigned* co = chunkOff + ((size_t)p * NCHUNK + c) * RSIZE;
    for (int r = threadIdx.x; r < RSIZE; r += 256) {
        int n = (p << RBITS) + r;
        cursor[r] = (n < N) ? (unsigned)rowStart[n] + co[r] : 0u;
    }
    __syncthreads();
    const int e0 = c * CS, e1 = min(E, e0 + CS);
    const int eA = e0 + ((e1 - e0) & ~3);
    for (int e = e0 + threadIdx.x * 4; e + 4 <= e1; e += 1024) {
        int4 d = *(const int4*)(dst + e);
        if ((d.x >> RBITS) == p) { unsigned q = atomicAdd(&cursor[d.x & (RSIZE - 1)], 1u); csrSrc[q] = src[e]; }
        if ((d.y >> RBITS) == p) { unsigned q = atomicAdd(&cursor[d.y & (RSIZE - 1)], 1u); csrSrc[q] = src[e + 1]; }
        if ((d.z >> RBITS) == p) { unsigned q = atomicAdd(&cursor[d.z & (RSIZE - 1)], 1u); csrSrc[q] = src[e + 2]; }
        if ((d.w >> RBITS) == p) { unsigned q = atomicAdd(&cursor[d.w & (RSIZE - 1)], 1u); csrSrc[q] = src[e + 3]; }
    }
    for (int e = eA + threadIdx.x; e < e1; e += 256) {
        int d = dst[e];
        if ((d >> RBITS) == p) { unsigned q = atomicAdd(&cursor[d & (RSIZE - 1)], 1u); csrSrc[q] = src[e]; }
    }
}

// ---------------------------------------------------------------- MFMA GEMM (bf16), fp32 input (layer 1); fp8 output
__global__ __launch_bounds__(512)
void gemm_mfma_kernel(const float* __restrict__ Ain, const float* __restrict__ W,
                      const float* __restrict__ scale, unsigned char* __restrict__ C,
                      int M, int nStrips)
{
    __shared__ ushort WTAs[64 * 132]; // half W^T staging, then As[64][132]
    __shared__ float  sScale[64];
    ushort* WT = WTAs;
    ushort* As = WTAs;

    const int tid  = threadIdx.x;
    const int wv   = tid >> 6;
    const int lane = tid & 63;
    const int rowHalf = wv >> 2;
    const int colQ = wv & 3;
    const int l15  = lane & 15;
    const int quad = lane >> 4;

    short8 bfrag[2][4];
#pragma unroll
    for (int hh = 0; hh < 2; ++hh) {
        if (hh) __syncthreads();
        for (int it = 0; it < 4; ++it) {
            int fid = tid + (it << 9);
            int k   = fid >> 4;
            int cl  = (fid & 15) << 2;
            float4 w = *(const float4*)(W + (size_t)k * FEAT + hh * 64 + cl);
            WT[(cl + 0) * 132 + k] = f2bf(w.x);
            WT[(cl + 1) * 132 + k] = f2bf(w.y);
            WT[(cl + 2) * 132 + k] = f2bf(w.z);
            WT[(cl + 3) * 132 + k] = f2bf(w.w);
        }
        __syncthreads();
        if (((wv >> 1) & 1) == hh) {
            int cq = wv & 1;
#pragma unroll
            for (int ct = 0; ct < 2; ++ct) {
                int col = cq * 32 + ct * 16 + l15;
#pragma unroll
                for (int kst = 0; kst < 4; ++kst) {
                    int k = kst * 32 + quad * 8;
                    short4v lo = *(const short4v*)&WT[col * 132 + k];
                    short4v hi = *(const short4v*)&WT[col * 132 + k + 4];
                    bfrag[ct][kst] = __builtin_shufflevector(lo, hi, 0, 1, 2, 3, 4, 5, 6, 7);
                }
            }
        }
    }

    for (int s = blockIdx.x; s < nStrips; s += gridDim.x) {
        const int row0 = s << 6;
        __syncthreads();

#pragma unroll
        for (int it = 0; it < 2; ++it) {
            int fid = tid + (it << 9);
            int r   = fid >> 4;
            int seg = (fid & 15) << 3;
            int grow = row0 + r;
            short4v lo = {0, 0, 0, 0}, hi = {0, 0, 0, 0};
            if (grow < M) {
                const float* pa = Ain + (size_t)grow * FEAT + seg;
                float4 u0 = *(const float4*)(pa);
                float4 u1 = *(const float4*)(pa + 4);
                lo[0] = (short)f2bf(u0.x); lo[1] = (short)f2bf(u0.y);
                lo[2] = (short)f2bf(u0.z); lo[3] = (short)f2bf(u0.w);
                hi[0] = (short)f2bf(u1.x); hi[1] = (short)f2bf(u1.y);
                hi[2] = (short)f2bf(u1.z); hi[3] = (short)f2bf(u1.w);
            }
            *(short4v*)&As[r * 132 + seg]     = lo;
            *(short4v*)&As[r * 132 + seg + 4] = hi;
        }
        if (tid < 64) {
            int grow = row0 + tid;
            sScale[tid] = (grow < M) ? scale[grow] : 0.0f;
        }
        __syncthreads();

        f32x4 acc[2][2] = {};
#pragma unroll
        for (int kst = 0; kst < 4; ++kst) {
            int k = kst * 32 + quad * 8;
            short8 af[2];
#pragma unroll
            for (int rt = 0; rt < 2; ++rt) {
                int row = rowHalf * 32 + rt * 16 + l15;
                short4v lo = *(const short4v*)&As[row * 132 + k];
                short4v hi = *(const short4v*)&As[row * 132 + k + 4];
                af[rt] = __builtin_shufflevector(lo, hi, 0, 1, 2, 3, 4, 5, 6, 7);
            }
#pragma unroll
            for (int rt = 0; rt < 2; ++rt)
#pragma unroll
                for (int ct = 0; ct < 2; ++ct)
                    acc[rt][ct] = __builtin_amdgcn_mfma_f32_16x16x32_bf16(
                        af[rt], bfrag[ct][kst], acc[rt][ct], 0, 0, 0);
        }

#pragma unroll
        for (int rt = 0; rt < 2; ++rt) {
            int rbase = rowHalf * 32 + rt * 16 + quad * 4;
#pragma unroll
            for (int reg = 0; reg < 4; ++reg) {
                int rl = rbase + reg;
                int grow = row0 + rl;
                if (grow < M) {
                    float sc = sScale[rl];
#pragma unroll
                    for (int ct = 0; ct < 2; ++ct) {
                        int col = colQ * 32 + ct * 16 + l15;
                        C[(size_t)grow * FEAT + col] = enc8(acc[rt][ct][reg] * sc);
                    }
                }
            }
        }
    }
}

// ---------------------------------------------------------------- gather inner over fp8 rows (HW cvt decode)
// 16 lanes x 8B per row (8 fp8 feats per lane); 8 rows in flight; 4 cvt_pk per row.
__device__ __forceinline__ void gather_row(const unsigned char* __restrict__ t,
                                           const int* __restrict__ csrSrc,
                                           int s, int e, int gl, int h, int li,
                                           float a[8])
{
    for (int base = s; base < e; base += 32) {
        const int m = min(32, e - base);
        int idx = (base + gl < e) ? csrSrc[base + gl] : 0;
        for (int j0 = 0; j0 < m; j0 += 16) {
            int sx[8];
#pragma unroll
            for (int q = 0; q < 8; ++q)
                sx[q] = __shfl(idx, j0 + h + 2 * q, 32);
            uint2v w[8];
#pragma unroll
            for (int q = 0; q < 8; ++q) {
                w[q] = (uint2v){0u, 0u};
                if (j0 + h + 2 * q < m)
                    w[q] = *(const uint2v*)(t + (size_t)sx[q] * FEAT + li * 8);
            }
#pragma unroll
            for (int q = 0; q < 8; ++q) {
                f32x2 p0 = __builtin_amdgcn_cvt_pk_f32_fp8((int)w[q][0], false);
                f32x2 p1 = __builtin_amdgcn_cvt_pk_f32_fp8((int)w[q][0], true);
                f32x2 p2 = __builtin_amdgcn_cvt_pk_f32_fp8((int)w[q][1], false);
                f32x2 p3 = __builtin_amdgcn_cvt_pk_f32_fp8((int)w[q][1], true);
                a[0] += p0[0]; a[1] += p0[1];
                a[2] += p1[0]; a[3] += p1[1];
                a[4] += p2[0]; a[5] += p2[1];
                a[6] += p3[0]; a[7] += p3[1];
            }
        }
    }
}

// ---------------------------------------------------------------- fusedA: gather(t1 fp8)+relu -> GEMM(W2)*normOut -> t2 fp8
__global__ __launch_bounds__(512)
void fusedA_kernel(const unsigned char* __restrict__ t1, const int* __restrict__ rowStart,
                   const int* __restrict__ csrSrc, const float* __restrict__ normIn,
                   const float* __restrict__ bias, const float* __restrict__ W,
                   const float* __restrict__ normOut, unsigned char* __restrict__ t2, int N)
{
    __shared__ ushort WTAs[64 * 132]; // half W2^T staging, then As[64][132]
    __shared__ float  sScale[64];
    ushort* WT = WTAs;
    ushort* As = WTAs;

    const int tid  = threadIdx.x;
    const int wv   = tid >> 6;
    const int lane = tid & 63;
    const int rowHalf = wv >> 2;
    const int colQ = wv & 3;
    const int l15  = lane & 15;
    const int quad = lane >> 4;
    const int row0 = blockIdx.x << 6;

    short8 bfrag[2][4];
#pragma unroll
    for (int hh = 0; hh < 2; ++hh) {
        if (hh) __syncthreads();
        for (int it = 0; it < 4; ++it) {
            int fid = tid + (it << 9);
            int k   = fid >> 4;
            int cl  = (fid & 15) << 2;
            float4 w = *(const float4*)(W + (size_t)k * FEAT + hh * 64 + cl);
            WT[(cl + 0) * 132 + k] = f2bf(w.x);
            WT[(cl + 1) * 132 + k] = f2bf(w.y);
            WT[(cl + 2) * 132 + k] = f2bf(w.z);
            WT[(cl + 3) * 132 + k] = f2bf(w.w);
        }
        __syncthreads();
        if (((wv >> 1) & 1) == hh) {
            int cq = wv & 1;
#pragma unroll
            for (int ct = 0; ct < 2; ++ct) {
                int col = cq * 32 + ct * 16 + l15;
#pragma unroll
                for (int kst = 0; kst < 4; ++kst) {
                    int k = kst * 32 + quad * 8;
                    short4v lo = *(const short4v*)&WT[col * 132 + k];
                    short4v hi = *(const short4v*)&WT[col * 132 + k + 4];
                    bfrag[ct][kst] = __builtin_shufflevector(lo, hi, 0, 1, 2, 3, 4, 5, 6, 7);
                }
            }
        }
    }
    if (tid < 64) {
        int grow = row0 + tid;
        sScale[tid] = (grow < N) ? normOut[grow] : 0.0f;
    }
    __syncthreads();  // all WT reads done before As (alias) is written

    // gather phase: 16 groups of 32 lanes; group g handles rows g, g+16, g+32, g+48
    {
        const int g    = tid >> 5;
        const int gl   = tid & 31;
        const int h    = gl >> 4;
        const int li   = gl & 15;
        const float4 b0 = *(const float4*)(bias + li * 8);
        const float4 b1 = *(const float4*)(bias + li * 8 + 4);
        for (int i = g; i < 64; i += 16) {
            const int node = row0 + i;
            float a[8] = {0.f, 0.f, 0.f, 0.f, 0.f, 0.f, 0.f, 0.f};
            if (node < N) {
                gather_row(t1, csrSrc, rowStart[node], rowStart[node + 1], gl, h, li, a);
            }
#pragma unroll
            for (int k = 0; k < 8; ++k)
                a[k] += __shfl_xor(a[k], 16, 32);
            if (h == 0) {
                short8 o = {0, 0, 0, 0, 0, 0, 0, 0};
                if (node < N) {
                    float ni = normIn[node];
                    o[0] = (short)f2bf(fmaxf(fmaf(a[0], ni, b0.x), 0.0f));
                    o[1] = (short)f2bf(fmaxf(fmaf(a[1], ni, b0.y), 0.0f));
                    o[2] = (short)f2bf(fmaxf(fmaf(a[2], ni, b0.z), 0.0f));
                    o[3] = (short)f2bf(fmaxf(fmaf(a[3], ni, b0.w), 0.0f));
                    o[4] = (short)f2bf(fmaxf(fmaf(a[4], ni, b1.x), 0.0f));
                    o[5] = (short)f2bf(fmaxf(fmaf(a[5], ni, b1.y), 0.0f));
                    o[6] = (short)f2bf(fmaxf(fmaf(a[6], ni, b1.z), 0.0f));
                    o[7] = (short)f2bf(fmaxf(fmaf(a[7], ni, b1.w), 0.0f));
                }
                *(short8*)&As[i * 132 + li * 8] = o;
            }
        }
    }
    __syncthreads();

    // MFMA phase
    f32x4 acc[2][2] = {};
#pragma unroll
    for (int kst = 0; kst < 4; ++kst) {
        int k = kst * 32 + quad * 8;
        short8 af[2];
#pragma unroll
        for (int rt = 0; rt < 2; ++rt) {
            int row = rowHalf * 32 + rt * 16 + l15;
            short4v lo = *(const short4v*)&As[row * 132 + k];
            short4v hi = *(const short4v*)&As[row * 132 + k + 4];
            af[rt] = __builtin_shufflevector(lo, hi, 0, 1, 2, 3, 4, 5, 6, 7);
        }
#pragma unroll
        for (int rt = 0; rt < 2; ++rt)
#pragma unroll
            for (int ct = 0; ct < 2; ++ct)
                acc[rt][ct] = __builtin_amdgcn_mfma_f32_16x16x32_bf16(
                    af[rt], bfrag[ct][kst], acc[rt][ct], 0, 0, 0);
    }

#pragma unroll
    for (int rt = 0; rt < 2; ++rt) {
        int rbase = rowHalf * 32 + rt * 16 + quad * 4;
#pragma unroll
        for (int reg = 0; reg < 4; ++reg) {
            int rl = rbase + reg;
            int grow = row0 + rl;
            if (grow < N) {
                float sc = sScale[rl];
#pragma unroll
                for (int ct = 0; ct < 2; ++ct) {
                    int col = colQ * 32 + ct * 16 + l15;
                    t2[(size_t)grow * FEAT + col] = enc8(acc[rt][ct][reg] * sc);
                }
            }
        }
    }
}

// ---------------------------------------------------------------- fusedB: gather(t2 fp8)+relu -> per-block column partials
__global__ __launch_bounds__(256)
void fusedB_kernel(const unsigned char* __restrict__ t2, const int* __restrict__ rowStart,
                   const int* __restrict__ csrSrc, const float* __restrict__ normIn,
                   const float* __restrict__ bias, float* __restrict__ partials, int N)
{
    const int g    = threadIdx.x >> 5;
    const int gl   = threadIdx.x & 31;
    const int h    = gl >> 4;
    const int li   = gl & 15;
    const float4 b0 = *(const float4*)(bias + li * 8);
    const float4 b1 = *(const float4*)(bias + li * 8 + 4);
    const int stride = gridDim.x * 8;

    float racc[8] = {0.f, 0.f, 0.f, 0.f, 0.f, 0.f, 0.f, 0.f};
    for (int node = blockIdx.x * 8 + g; node < N; node += stride) {
        float a[8] = {0.f, 0.f, 0.f, 0.f, 0.f, 0.f, 0.f, 0.f};
        gather_row(t2, csrSrc, rowStart[node], rowStart[node + 1], gl, h, li, a);
#pragma unroll
        for (int k = 0; k < 8; ++k)
            a[k] += __shfl_xor(a[k], 16, 32);
        if (h == 0) {
            float ni = normIn[node];
            racc[0] += fmaxf(fmaf(a[0], ni, b0.x), 0.0f);
            racc[1] += fmaxf(fmaf(a[1], ni, b0.y), 0.0f);
            racc[2] += fmaxf(fmaf(a[2], ni, b0.z), 0.0f);
            racc[3] += fmaxf(fmaf(a[3], ni, b0.w), 0.0f);
            racc[4] += fmaxf(fmaf(a[4], ni, b1.x), 0.0f);
            racc[5] += fmaxf(fmaf(a[5], ni, b1.y), 0.0f);
            racc[6] += fmaxf(fmaf(a[6], ni, b1.z), 0.0f);
            racc[7] += fmaxf(fmaf(a[7], ni, b1.w), 0.0f);
        }
    }

    __shared__ float colsh[8][128];
    if (h == 0) {
#pragma unroll
        for (int k = 0; k < 8; ++k) colsh[g][li * 8 + k] = racc[k];
    }
    __syncthreads();
    if (threadIdx.x < 128) {
        float sum = 0.f;
#pragma unroll
        for (int gg = 0; gg < 8; ++gg) sum += colsh[gg][threadIdx.x];
        partials[(size_t)blockIdx.x * 128 + threadIdx.x] = sum;
    }
}

// ---------------------------------------------------------------- final: parallel reduce of partials + readout
__global__ __launch_bounds__(1024)
void final_kernel(const float* __restrict__ partials, const float* __restrict__ Wr,
                  const float* __restrict__ br, float* __restrict__ out, float invN, int G)
{
    __shared__ float cs[128];
    __shared__ float s0[128], s1[128];
    if (threadIdx.x < 128) cs[threadIdx.x] = 0.0f;
    __syncthreads();

    const int c4 = (threadIdx.x & 31) << 2;
    const int rg = threadIdx.x >> 5;
    f32x4 acc = {0.f, 0.f, 0.f, 0.f};
    for (int b = rg; b < G; b += 32) {
        f32x4 v = *(const f32x4*)(partials + (size_t)b * 128 + c4);
        acc += v;
    }
    atomicAdd(&cs[c4 + 0], acc[0]);
    atomicAdd(&cs[c4 + 1], acc[1]);
    atomicAdd(&cs[c4 + 2], acc[2]);
    atomicAdd(&cs[c4 + 3], acc[3]);
    __syncthreads();

    const int j = threadIdx.x;
    if (j < 128) {
        float hg = cs[j] * invN;
        s0[j] = hg * Wr[2 * j + 0];
        s1[j] = hg * Wr[2 * j + 1];
    }
    __syncthreads();
    for (int off = 64; off > 0; off >>= 1) {
        if (j < off) { s0[j] += s0[j + off]; s1[j] += s1[j + off]; }
        __syncthreads();
    }
    if (j == 0) {
        out[0] = s0[0] + br[0];
        out[1] = s1[0] + br[1];
    }
}

// ---------------------------------------------------------------- launch
extern "C" void kernel_launch(void* const* d_in, const int* in_sizes, int n_in,
                              void* d_out, int out_size, void* d_ws, size_t ws_size,
                              hipStream_t stream)
{
    const float* x   = (const float*)d_in[0];
    const int*   src = (const int*)d_in[1];
    const int*   dst = (const int*)d_in[2];
    const float* W1  = (const float*)d_in[3];
    const float* b1  = (const float*)d_in[4];
    const float* W2  = (const float*)d_in[5];
    const float* b2  = (const float*)d_in[6];
    const float* Wr  = (const float*)d_in[7];
    const float* br  = (const float*)d_in[8];
    float* out = (float*)d_out;

    const int N = in_sizes[0] / FEAT;         // 50000
    const int E = in_sizes[1];                // 640000
    const int NP = ((N + 255) / 256) * 256;
    const int NB = (N + 255) / 256;           // 196
    const int P  = (N + RSIZE - 1) / RSIZE;   // 13
    const int CS = (((E + NCHUNK - 1) / NCHUNK) + 3) & ~3;  // 4-aligned chunk
    const int GB = 1024;                      // fusedB blocks

    // workspace layout
    char* p = (char*)d_ws;
    unsigned* partial = (unsigned*)p;    p += (size_t)2 * P * NCHUNK * RSIZE * 4;
    int*    blockSums = (int*)p;         p += 256 * 4;
    int*    cntIn     = (int*)p;         p += (size_t)NP * 4;
    float*  normOut   = (float*)p;       p += (size_t)NP * 4;
    float*  normIn    = (float*)p;       p += (size_t)NP * 4;
    int*    rowStart  = (int*)p;         p += (size_t)(NP + 64) * 4;
    int*    csrSrc    = (int*)p;         p += (size_t)E * 4;
    float*  partials  = (float*)p;       p += (size_t)GB * 128 * 4;
    unsigned char* bufT1 = (unsigned char*)p;  p += (size_t)N * FEAT;
    unsigned char* bufT2 = (unsigned char*)p;  p += (size_t)N * FEAT;

    unsigned* partialOut = partial;                                  // job 0 (src)
    unsigned* partialIn  = partial + (size_t)P * NCHUNK * RSIZE;     // job 1 (dst)

    // CSR + degree pipeline (LDS-partitioned, no memory-side atomics)
    hist_kernel<<<dim3(NCHUNK, P, 2), 256, 0, stream>>>(src, dst, partial, E, CS);
    merge_kernel<<<NB, 256, 0, stream>>>(partialOut, partialIn, cntIn, normOut, normIn, blockSums, N);
    rowstart_kernel<<<NB, 256, 0, stream>>>(cntIn, blockSums, rowStart, N, NB, E);
    fill_kernel<<<dim3(NCHUNK, P), 256, 0, stream>>>(src, dst, rowStart, partialIn, csrSrc, N, E, CS);

    const int nStrips = (N + 63) / 64;        // 782

    // layer 1 GEMM: t1 = fp8((x W1) * normOut64)
    gemm_mfma_kernel<<<nStrips, 512, 0, stream>>>(x, W1, normOut, bufT1, N, nStrips);

    // layer 1 gather + relu + layer 2 GEMM fused
    fusedA_kernel<<<nStrips, 512, 0, stream>>>(bufT1, rowStart, csrSrc, normIn, b1, W2, normOut, bufT2, N);

    // layer 2 gather + relu + column partial sums
    fusedB_kernel<<<GB, 256, 0, stream>>>(bufT2, rowStart, csrSrc, normIn, b2, partials, N);

    // parallel reduce + readout
    final_kernel<<<1, 1024, 0, stream>>>(partials, Wr, br, out, 1.0f / (float)N, GB);
}

// Round 15
// 209.794 us; speedup vs baseline: 1.2124x; 1.0103x over previous
//
#include <hip/hip_runtime.h>
#include <hip/hip_bf16.h>

#define FEAT 128
#define RBITS 12
#define RSIZE 4096           // partition width (16 KB LDS of u32)
#define NCHUNK 32            // edge chunks

typedef __attribute__((ext_vector_type(8))) short short8;
typedef __attribute__((ext_vector_type(4))) short short4v;
typedef __attribute__((ext_vector_type(4))) float f32x4;
typedef __attribute__((ext_vector_type(2))) float f32x2;
typedef __attribute__((ext_vector_type(2))) unsigned uint2v;

__device__ __forceinline__ ushort f2bf(float f) {
    union { float f; unsigned u; } v; v.f = f;
    unsigned u = v.u;
    unsigned r = 0x7fffu + ((u >> 16) & 1u);
    return (ushort)((u + r) >> 16);
}
__device__ __forceinline__ float bf2f(short s) {
    union { unsigned u; float f; } v;
    v.u = ((unsigned)(ushort)s) << 16;
    return v.f;
}

// ---- fp8 e4m3 via HW converts (gfx940+ fp8-conversion-insts) ----
// x64 pre-scale is folded into normOut (x64) / normIn (/64) at merge time.
__device__ __forceinline__ unsigned char enc8(float f) {
    int r = __builtin_amdgcn_cvt_pk_fp8_f32(f, f, 0, false);
    return (unsigned char)(r & 0xFF);
}

// ---------------------------------------------------------------- A: partial histograms (LDS atomics only)
// Also zeroes the blockSums flag array for the fused scanrow kernel.
__global__ __launch_bounds__(256)
void hist_kernel(const int* __restrict__ src, const int* __restrict__ dst,
                 unsigned* __restrict__ partial, int* __restrict__ blockSums,
                 int E, int CS)
{
    __shared__ unsigned hist[RSIZE];
    const int c = blockIdx.x, p = blockIdx.y, job = blockIdx.z;
    const int* __restrict__ idx = job ? dst : src;
    if (c == 0 && p == 0 && job == 0 && threadIdx.x < 256)
        blockSums[threadIdx.x] = 0;          // unpublished (flag bit 30 clear)
    for (int r = threadIdx.x; r < RSIZE; r += 256) hist[r] = 0;
    __syncthreads();
    const int e0 = c * CS, e1 = min(E, e0 + CS);
    const int eA = e0 + ((e1 - e0) & ~3);
    for (int e = e0 + threadIdx.x * 4; e + 4 <= e1; e += 1024) {
        int4 v = *(const int4*)(idx + e);
        if ((v.x >> RBITS) == p) atomicAdd(&hist[v.x & (RSIZE - 1)], 1u);
        if ((v.y >> RBITS) == p) atomicAdd(&hist[v.y & (RSIZE - 1)], 1u);
        if ((v.z >> RBITS) == p) atomicAdd(&hist[v.z & (RSIZE - 1)], 1u);
        if ((v.w >> RBITS) == p) atomicAdd(&hist[v.w & (RSIZE - 1)], 1u);
    }
    for (int e = eA + threadIdx.x; e < e1; e += 256) {
        int v = idx[e];
        if ((v >> RBITS) == p) atomicAdd(&hist[v & (RSIZE - 1)], 1u);
    }
    __syncthreads();
    unsigned* outp = partial +
        (((size_t)job * gridDim.y + p) * NCHUNK + c) * RSIZE;
    for (int r = threadIdx.x; r < RSIZE; r += 256) outp[r] = hist[r];
}

// ---------------------------------------------------------------- B+C fused: merge partials -> norms/chunk offsets,
// then rowStart via decoupled lookback (all NB=196 blocks co-resident on 256 CUs -> spin is deadlock-free).
// Publish/read via device-scope atomics (memory-side) since per-XCD L2s are not coherent.
__global__ __launch_bounds__(256)
void scanrow_kernel(const unsigned* __restrict__ partialOut, unsigned* __restrict__ partialIn,
                    float* __restrict__ normOut, float* __restrict__ normIn,
                    int* __restrict__ blockSums, int* __restrict__ rowStart,
                    int N, int NB, int E)
{
    __shared__ int sh[256];
    __shared__ int red[256];
    const int b = blockIdx.x, t = threadIdx.x;
    const int n = b * 256 + t;
    unsigned off = 0;
    if (n < N) {
        const int p = n >> RBITS, r = n & (RSIZE - 1);
        const size_t base = (size_t)p * NCHUNK * RSIZE + r;
        unsigned so = 0;
#pragma unroll 8
        for (int c = 0; c < NCHUNK; ++c) so += partialOut[base + (size_t)c * RSIZE];
#pragma unroll 8
        for (int c = 0; c < NCHUNK; ++c) {
            size_t i = base + (size_t)c * RSIZE;
            unsigned tv = partialIn[i];
            partialIn[i] = off;
            off += tv;
        }
        normIn[n]  = off ? rsqrtf((float)off) * (1.0f / 64.0f) : 0.0f;
        normOut[n] = so  ? rsqrtf((float)so)  * 64.0f          : 0.0f;
    }

    // block aggregate -> publish EARLY (before local scan) to unblock successors
    red[t] = (int)off;
    __syncthreads();
    for (int o = 128; o > 0; o >>= 1) {
        if (t < o) red[t] += red[t + o];
        __syncthreads();
    }
    if (t == 0)
        atomicExch(&blockSums[b], red[0] | 0x40000000);   // value carries its own flag

    // local inclusive scan
    sh[t] = (int)off;
    __syncthreads();
    for (int o = 1; o < 256; o <<= 1) {
        int u = (t >= o) ? sh[t - o] : 0;
        __syncthreads();
        sh[t] += u;
        __syncthreads();
    }

    // lookback: thread t spins on predecessor block t (parallel across lanes)
    int pre = 0;
    if (t < b) {
        int v;
        do { v = atomicAdd(&blockSums[t], 0); } while (!(v & 0x40000000));
        pre = v & 0x3FFFFFFF;
    }
    red[t] = pre;
    __syncthreads();
    for (int o = 128; o > 0; o >>= 1) {
        if (t < o) red[t] += red[t + o];
        __syncthreads();
    }
    const int blockPre = red[0];
    if (n < N) rowStart[n] = blockPre + sh[t] - (int)off;
    if (b == NB - 1 && t == 0) rowStart[N] = E;
}

// ---------------------------------------------------------------- fill: LDS cursor counting sort
__global__ __launch_bounds__(256)
void fill_kernel(const int* __restrict__ src, const int* __restrict__ dst,
                 const int* __restrict__ rowStart, const unsigned* __restrict__ chunkOff,
                 int* __restrict__ csrSrc, int N, int E, int CS)
{
    __shared__ unsigned cursor[RSIZE];
    const int c = blockIdx.x, p = blockIdx.y;
    const unsigned* co = chunkOff + ((size_t)p * NCHUNK + c) * RSIZE;
    for (int r = threadIdx.x; r < RSIZE; r += 256) {
        int n = (p << RBITS) + r;
        cursor[r] = (n < N) ? (unsigned)rowStart[n] + co[r] : 0u;
    }
    __syncthreads();
    const int e0 = c * CS, e1 = min(E, e0 + CS);
    const int eA = e0 + ((e1 - e0) & ~3);
    for (int e = e0 + threadIdx.x * 4; e + 4 <= e1; e += 1024) {
        int4 d = *(const int4*)(dst + e);
        if ((d.x >> RBITS) == p) { unsigned q = atomicAdd(&cursor[d.x & (RSIZE - 1)], 1u); csrSrc[q] = src[e]; }
        if ((d.y >> RBITS) == p) { unsigned q = atomicAdd(&cursor[d.y & (RSIZE - 1)], 1u); csrSrc[q] = src[e + 1]; }
        if ((d.z >> RBITS) == p) { unsigned q = atomicAdd(&cursor[d.z & (RSIZE - 1)], 1u); csrSrc[q] = src[e + 2]; }
        if ((d.w >> RBITS) == p) { unsigned q = atomicAdd(&cursor[d.w & (RSIZE - 1)], 1u); csrSrc[q] = src[e + 3]; }
    }
    for (int e = eA + threadIdx.x; e < e1; e += 256) {
        int d = dst[e];
        if ((d >> RBITS) == p) { unsigned q = atomicAdd(&cursor[d & (RSIZE - 1)], 1u); csrSrc[q] = src[e]; }
    }
}

// ---------------------------------------------------------------- MFMA GEMM (bf16), fp32 input (layer 1); fp8 output
__global__ __launch_bounds__(512)
void gemm_mfma_kernel(const float* __restrict__ Ain, const float* __restrict__ W,
                      const float* __restrict__ scale, unsigned char* __restrict__ C,
                      int M, int nStrips)
{
    __shared__ ushort WTAs[64 * 132]; // half W^T staging, then As[64][132]
    __shared__ float  sScale[64];
    ushort* WT = WTAs;
    ushort* As = WTAs;

    const int tid  = threadIdx.x;
    const int wv   = tid >> 6;
    const int lane = tid & 63;
    const int rowHalf = wv >> 2;
    const int colQ = wv & 3;
    const int l15  = lane & 15;
    const int quad = lane >> 4;

    short8 bfrag[2][4];
#pragma unroll
    for (int hh = 0; hh < 2; ++hh) {
        if (hh) __syncthreads();
        for (int it = 0; it < 4; ++it) {
            int fid = tid + (it << 9);
            int k   = fid >> 4;
            int cl  = (fid & 15) << 2;
            float4 w = *(const float4*)(W + (size_t)k * FEAT + hh * 64 + cl);
            WT[(cl + 0) * 132 + k] = f2bf(w.x);
            WT[(cl + 1) * 132 + k] = f2bf(w.y);
            WT[(cl + 2) * 132 + k] = f2bf(w.z);
            WT[(cl + 3) * 132 + k] = f2bf(w.w);
        }
        __syncthreads();
        if (((wv >> 1) & 1) == hh) {
            int cq = wv & 1;
#pragma unroll
            for (int ct = 0; ct < 2; ++ct) {
                int col = cq * 32 + ct * 16 + l15;
#pragma unroll
                for (int kst = 0; kst < 4; ++kst) {
                    int k = kst * 32 + quad * 8;
                    short4v lo = *(const short4v*)&WT[col * 132 + k];
                    short4v hi = *(const short4v*)&WT[col * 132 + k + 4];
                    bfrag[ct][kst] = __builtin_shufflevector(lo, hi, 0, 1, 2, 3, 4, 5, 6, 7);
                }
            }
        }
    }

    for (int s = blockIdx.x; s < nStrips; s += gridDim.x) {
        const int row0 = s << 6;
        __syncthreads();

#pragma unroll
        for (int it = 0; it < 2; ++it) {
            int fid = tid + (it << 9);
            int r   = fid >> 4;
            int seg = (fid & 15) << 3;
            int grow = row0 + r;
            short4v lo = {0, 0, 0, 0}, hi = {0, 0, 0, 0};
            if (grow < M) {
                const float* pa = Ain + (size_t)grow * FEAT + seg;
                float4 u0 = *(const float4*)(pa);
                float4 u1 = *(const float4*)(pa + 4);
                lo[0] = (short)f2bf(u0.x); lo[1] = (short)f2bf(u0.y);
                lo[2] = (short)f2bf(u0.z); lo[3] = (short)f2bf(u0.w);
                hi[0] = (short)f2bf(u1.x); hi[1] = (short)f2bf(u1.y);
                hi[2] = (short)f2bf(u1.z); hi[3] = (short)f2bf(u1.w);
            }
            *(short4v*)&As[r * 132 + seg]     = lo;
            *(short4v*)&As[r * 132 + seg + 4] = hi;
        }
        if (tid < 64) {
            int grow = row0 + tid;
            sScale[tid] = (grow < M) ? scale[grow] : 0.0f;
        }
        __syncthreads();

        f32x4 acc[2][2] = {};
#pragma unroll
        for (int kst = 0; kst < 4; ++kst) {
            int k = kst * 32 + quad * 8;
            short8 af[2];
#pragma unroll
            for (int rt = 0; rt < 2; ++rt) {
                int row = rowHalf * 32 + rt * 16 + l15;
                short4v lo = *(const short4v*)&As[row * 132 + k];
                short4v hi = *(const short4v*)&As[row * 132 + k + 4];
                af[rt] = __builtin_shufflevector(lo, hi, 0, 1, 2, 3, 4, 5, 6, 7);
            }
#pragma unroll
            for (int rt = 0; rt < 2; ++rt)
#pragma unroll
                for (int ct = 0; ct < 2; ++ct)
                    acc[rt][ct] = __builtin_amdgcn_mfma_f32_16x16x32_bf16(
                        af[rt], bfrag[ct][kst], acc[rt][ct], 0, 0, 0);
        }

#pragma unroll
        for (int rt = 0; rt < 2; ++rt) {
            int rbase = rowHalf * 32 + rt * 16 + quad * 4;
#pragma unroll
            for (int reg = 0; reg < 4; ++reg) {
                int rl = rbase + reg;
                int grow = row0 + rl;
                if (grow < M) {
                    float sc = sScale[rl];
#pragma unroll
                    for (int ct = 0; ct < 2; ++ct) {
                        int col = colQ * 32 + ct * 16 + l15;
                        C[(size_t)grow * FEAT + col] = enc8(acc[rt][ct][reg] * sc);
                    }
                }
            }
        }
    }
}

// ---------------------------------------------------------------- gather inner over fp8 rows (HW cvt decode)
__device__ __forceinline__ void gather_row(const unsigned char* __restrict__ t,
                                           const int* __restrict__ csrSrc,
                                           int s, int e, int gl, int h, int li,
                                           float a[8])
{
    for (int base = s; base < e; base += 32) {
        const int m = min(32, e - base);
        int idx = (base + gl < e) ? csrSrc[base + gl] : 0;
        for (int j0 = 0; j0 < m; j0 += 16) {
            int sx[8];
#pragma unroll
            for (int q = 0; q < 8; ++q)
                sx[q] = __shfl(idx, j0 + h + 2 * q, 32);
            uint2v w[8];
#pragma unroll
            for (int q = 0; q < 8; ++q) {
                w[q] = (uint2v){0u, 0u};
                if (j0 + h + 2 * q < m)
                    w[q] = *(const uint2v*)(t + (size_t)sx[q] * FEAT + li * 8);
            }
#pragma unroll
            for (int q = 0; q < 8; ++q) {
                f32x2 p0 = __builtin_amdgcn_cvt_pk_f32_fp8((int)w[q][0], false);
                f32x2 p1 = __builtin_amdgcn_cvt_pk_f32_fp8((int)w[q][0], true);
                f32x2 p2 = __builtin_amdgcn_cvt_pk_f32_fp8((int)w[q][1], false);
                f32x2 p3 = __builtin_amdgcn_cvt_pk_f32_fp8((int)w[q][1], true);
                a[0] += p0[0]; a[1] += p0[1];
                a[2] += p1[0]; a[3] += p1[1];
                a[4] += p2[0]; a[5] += p2[1];
                a[6] += p3[0]; a[7] += p3[1];
            }
        }
    }
}

// ---------------------------------------------------------------- fusedA: gather(t1 fp8)+relu -> GEMM(W2)*normOut -> t2 fp8
__global__ __launch_bounds__(512)
void fusedA_kernel(const unsigned char* __restrict__ t1, const int* __restrict__ rowStart,
                   const int* __restrict__ csrSrc, const float* __restrict__ normIn,
                   const float* __restrict__ bias, const float* __restrict__ W,
                   const float* __restrict__ normOut, unsigned char* __restrict__ t2, int N)
{
    __shared__ ushort WTAs[64 * 132]; // half W2^T staging, then As[64][132]
    __shared__ float  sScale[64];
    ushort* WT = WTAs;
    ushort* As = WTAs;

    const int tid  = threadIdx.x;
    const int wv   = tid >> 6;
    const int lane = tid & 63;
    const int rowHalf = wv >> 2;
    const int colQ = wv & 3;
    const int l15  = lane & 15;
    const int quad = lane >> 4;
    const int row0 = blockIdx.x << 6;

    short8 bfrag[2][4];
#pragma unroll
    for (int hh = 0; hh < 2; ++hh) {
        if (hh) __syncthreads();
        for (int it = 0; it < 4; ++it) {
            int fid = tid + (it << 9);
            int k   = fid >> 4;
            int cl  = (fid & 15) << 2;
            float4 w = *(const float4*)(W + (size_t)k * FEAT + hh * 64 + cl);
            WT[(cl + 0) * 132 + k] = f2bf(w.x);
            WT[(cl + 1) * 132 + k] = f2bf(w.y);
            WT[(cl + 2) * 132 + k] = f2bf(w.z);
            WT[(cl + 3) * 132 + k] = f2bf(w.w);
        }
        __syncthreads();
        if (((wv >> 1) & 1) == hh) {
            int cq = wv & 1;
#pragma unroll
            for (int ct = 0; ct < 2; ++ct) {
                int col = cq * 32 + ct * 16 + l15;
#pragma unroll
                for (int kst = 0; kst < 4; ++kst) {
                    int k = kst * 32 + quad * 8;
                    short4v lo = *(const short4v*)&WT[col * 132 + k];
                    short4v hi = *(const short4v*)&WT[col * 132 + k + 4];
                    bfrag[ct][kst] = __builtin_shufflevector(lo, hi, 0, 1, 2, 3, 4, 5, 6, 7);
                }
            }
        }
    }
    if (tid < 64) {
        int grow = row0 + tid;
        sScale[tid] = (grow < N) ? normOut[grow] : 0.0f;
    }
    __syncthreads();  // all WT reads done before As (alias) is written

    // gather phase: 16 groups of 32 lanes; group g handles rows g, g+16, g+32, g+48
    {
        const int g    = tid >> 5;
        const int gl   = tid & 31;
        const int h    = gl >> 4;
        const int li   = gl & 15;
        const float4 b0 = *(const float4*)(bias + li * 8);
        const float4 b1 = *(const float4*)(bias + li * 8 + 4);
        for (int i = g; i < 64; i += 16) {
            const int node = row0 + i;
            float a[8] = {0.f, 0.f, 0.f, 0.f, 0.f, 0.f, 0.f, 0.f};
            if (node < N) {
                gather_row(t1, csrSrc, rowStart[node], rowStart[node + 1], gl, h, li, a);
            }
#pragma unroll
            for (int k = 0; k < 8; ++k)
                a[k] += __shfl_xor(a[k], 16, 32);
            if (h == 0) {
                short8 o = {0, 0, 0, 0, 0, 0, 0, 0};
                if (node < N) {
                    float ni = normIn[node];
                    o[0] = (short)f2bf(fmaxf(fmaf(a[0], ni, b0.x), 0.0f));
                    o[1] = (short)f2bf(fmaxf(fmaf(a[1], ni, b0.y), 0.0f));
                    o[2] = (short)f2bf(fmaxf(fmaf(a[2], ni, b0.z), 0.0f));
                    o[3] = (short)f2bf(fmaxf(fmaf(a[3], ni, b0.w), 0.0f));
                    o[4] = (short)f2bf(fmaxf(fmaf(a[4], ni, b1.x), 0.0f));
                    o[5] = (short)f2bf(fmaxf(fmaf(a[5], ni, b1.y), 0.0f));
                    o[6] = (short)f2bf(fmaxf(fmaf(a[6], ni, b1.z), 0.0f));
                    o[7] = (short)f2bf(fmaxf(fmaf(a[7], ni, b1.w), 0.0f));
                }
                *(short8*)&As[i * 132 + li * 8] = o;
            }
        }
    }
    __syncthreads();

    // MFMA phase
    f32x4 acc[2][2] = {};
#pragma unroll
    for (int kst = 0; kst < 4; ++kst) {
        int k = kst * 32 + quad * 8;
        short8 af[2];
#pragma unroll
        for (int rt = 0; rt < 2; ++rt) {
            int row = rowHalf * 32 + rt * 16 + l15;
            short4v lo = *(const short4v*)&As[row * 132 + k];
            short4v hi = *(const short4v*)&As[row * 132 + k + 4];
            af[rt] = __builtin_shufflevector(lo, hi, 0, 1, 2, 3, 4, 5, 6, 7);
        }
#pragma unroll
        for (int rt = 0; rt < 2; ++rt)
#pragma unroll
            for (int ct = 0; ct < 2; ++ct)
                acc[rt][ct] = __builtin_amdgcn_mfma_f32_16x16x32_bf16(
                    af[rt], bfrag[ct][kst], acc[rt][ct], 0, 0, 0);
    }

#pragma unroll
    for (int rt = 0; rt < 2; ++rt) {
        int rbase = rowHalf * 32 + rt * 16 + quad * 4;
#pragma unroll
        for (int reg = 0; reg < 4; ++reg) {
            int rl = rbase + reg;
            int grow = row0 + rl;
            if (grow < N) {
                float sc = sScale[rl];
#pragma unroll
                for (int ct = 0; ct < 2; ++ct) {
                    int col = colQ * 32 + ct * 16 + l15;
                    t2[(size_t)grow * FEAT + col] = enc8(acc[rt][ct][reg] * sc);
                }
            }
        }
    }
}

// ---------------------------------------------------------------- fusedB: gather(t2 fp8)+relu -> per-block column partials
__global__ __launch_bounds__(256)
void fusedB_kernel(const unsigned char* __restrict__ t2, const int* __restrict__ rowStart,
                   const int* __restrict__ csrSrc, const float* __restrict__ normIn,
                   const float* __restrict__ bias, float* __restrict__ partials, int N)
{
    const int g    = threadIdx.x >> 5;
    const int gl   = threadIdx.x & 31;
    const int h    = gl >> 4;
    const int li   = gl & 15;
    const float4 b0 = *(const float4*)(bias + li * 8);
    const float4 b1 = *(const float4*)(bias + li * 8 + 4);
    const int stride = gridDim.x * 8;

    float racc[8] = {0.f, 0.f, 0.f, 0.f, 0.f, 0.f, 0.f, 0.f};
    for (int node = blockIdx.x * 8 + g; node < N; node += stride) {
        float a[8] = {0.f, 0.f, 0.f, 0.f, 0.f, 0.f, 0.f, 0.f};
        gather_row(t2, csrSrc, rowStart[node], rowStart[node + 1], gl, h, li, a);
#pragma unroll
        for (int k = 0; k < 8; ++k)
            a[k] += __shfl_xor(a[k], 16, 32);
        if (h == 0) {
            float ni = normIn[node];
            racc[0] += fmaxf(fmaf(a[0], ni, b0.x), 0.0f);
            racc[1] += fmaxf(fmaf(a[1], ni, b0.y), 0.0f);
            racc[2] += fmaxf(fmaf(a[2], ni, b0.z), 0.0f);
            racc[3] += fmaxf(fmaf(a[3], ni, b0.w), 0.0f);
            racc[4] += fmaxf(fmaf(a[4], ni, b1.x), 0.0f);
            racc[5] += fmaxf(fmaf(a[5], ni, b1.y), 0.0f);
            racc[6] += fmaxf(fmaf(a[6], ni, b1.z), 0.0f);
            racc[7] += fmaxf(fmaf(a[7], ni, b1.w), 0.0f);
        }
    }

    __shared__ float colsh[8][128];
    if (h == 0) {
#pragma unroll
        for (int k = 0; k < 8; ++k) colsh[g][li * 8 + k] = racc[k];
    }
    __syncthreads();
    if (threadIdx.x < 128) {
        float sum = 0.f;
#pragma unroll
        for (int gg = 0; gg < 8; ++gg) sum += colsh[gg][threadIdx.x];
        partials[(size_t)blockIdx.x * 128 + threadIdx.x] = sum;
    }
}

// ---------------------------------------------------------------- final: parallel reduce of partials + readout
__global__ __launch_bounds__(1024)
void final_kernel(const float* __restrict__ partials, const float* __restrict__ Wr,
                  const float* __restrict__ br, float* __restrict__ out, float invN, int G)
{
    __shared__ float cs[128];
    __shared__ float s0[128], s1[128];
    if (threadIdx.x < 128) cs[threadIdx.x] = 0.0f;
    __syncthreads();

    const int c4 = (threadIdx.x & 31) << 2;
    const int rg = threadIdx.x >> 5;
    f32x4 acc = {0.f, 0.f, 0.f, 0.f};
    for (int b = rg; b < G; b += 32) {
        f32x4 v = *(const f32x4*)(partials + (size_t)b * 128 + c4);
        acc += v;
    }
    atomicAdd(&cs[c4 + 0], acc[0]);
    atomicAdd(&cs[c4 + 1], acc[1]);
    atomicAdd(&cs[c4 + 2], acc[2]);
    atomicAdd(&cs[c4 + 3], acc[3]);
    __syncthreads();

    const int j = threadIdx.x;
    if (j < 128) {
        float hg = cs[j] * invN;
        s0[j] = hg * Wr[2 * j + 0];
        s1[j] = hg * Wr[2 * j + 1];
    }
    __syncthreads();
    for (int off = 64; off > 0; off >>= 1) {
        if (j < off) { s0[j] += s0[j + off]; s1[j] += s1[j + off]; }
        __syncthreads();
    }
    if (j == 0) {
        out[0] = s0[0] + br[0];
        out[1] = s1[0] + br[1];
    }
}

// ---------------------------------------------------------------- launch
extern "C" void kernel_launch(void* const* d_in, const int* in_sizes, int n_in,
                              void* d_out, int out_size, void* d_ws, size_t ws_size,
                              hipStream_t stream)
{
    const float* x   = (const float*)d_in[0];
    const int*   src = (const int*)d_in[1];
    const int*   dst = (const int*)d_in[2];
    const float* W1  = (const float*)d_in[3];
    const float* b1  = (const float*)d_in[4];
    const float* W2  = (const float*)d_in[5];
    const float* b2  = (const float*)d_in[6];
    const float* Wr  = (const float*)d_in[7];
    const float* br  = (const float*)d_in[8];
    float* out = (float*)d_out;

    const int N = in_sizes[0] / FEAT;         // 50000
    const int E = in_sizes[1];                // 640000
    const int NP = ((N + 255) / 256) * 256;
    const int NB = (N + 255) / 256;           // 196
    const int P  = (N + RSIZE - 1) / RSIZE;   // 13
    const int CS = (((E + NCHUNK - 1) / NCHUNK) + 3) & ~3;  // 4-aligned chunk
    const int GB = 1024;                      // fusedB blocks

    // workspace layout
    char* p = (char*)d_ws;
    unsigned* partial = (unsigned*)p;    p += (size_t)2 * P * NCHUNK * RSIZE * 4;
    int*    blockSums = (int*)p;         p += 256 * 4;
    float*  normOut   = (float*)p;       p += (size_t)NP * 4;
    float*  normIn    = (float*)p;       p += (size_t)NP * 4;
    int*    rowStart  = (int*)p;         p += (size_t)(NP + 64) * 4;
    int*    csrSrc    = (int*)p;         p += (size_t)E * 4;
    float*  partials  = (float*)p;       p += (size_t)GB * 128 * 4;
    unsigned char* bufT1 = (unsigned char*)p;  p += (size_t)N * FEAT;
    unsigned char* bufT2 = (unsigned char*)p;  p += (size_t)N * FEAT;

    unsigned* partialOut = partial;                                  // job 0 (src)
    unsigned* partialIn  = partial + (size_t)P * NCHUNK * RSIZE;     // job 1 (dst)

    // CSR + degree pipeline (LDS-partitioned; merge+rowstart fused via decoupled lookback)
    hist_kernel<<<dim3(NCHUNK, P, 2), 256, 0, stream>>>(src, dst, partial, blockSums, E, CS);
    scanrow_kernel<<<NB, 256, 0, stream>>>(partialOut, partialIn, normOut, normIn,
                                           blockSums, rowStart, N, NB, E);
    fill_kernel<<<dim3(NCHUNK, P), 256, 0, stream>>>(src, dst, rowStart, partialIn, csrSrc, N, E, CS);

    const int nStrips = (N + 63) / 64;        // 782

    // layer 1 GEMM: t1 = fp8((x W1) * normOut64)
    gemm_mfma_kernel<<<nStrips, 512, 0, stream>>>(x, W1, normOut, bufT1, N, nStrips);

    // layer 1 gather + relu + layer 2 GEMM fused
    fusedA_kernel<<<nStrips, 512, 0, stream>>>(bufT1, rowStart, csrSrc, normIn, b1, W2, normOut, bufT2, N);

    // layer 2 gather + relu + column partial sums
    fusedB_kernel<<<GB, 256, 0, stream>>>(bufT2, rowStart, csrSrc, normIn, b2, partials, N);

    // parallel reduce + readout
    final_kernel<<<1, 1024, 0, stream>>>(partials, Wr, br, out, 1.0f / (float)N, GB);
}